// Round 13
// baseline (37.279 us; speedup 1.0000x reference)
//
#include <hip/hip_runtime.h>
#include <hip/hip_bf16.h>

#define B_SZ   256
#define N_IN   128
#define F_IN   64
#define G_SZ   128
#define F_OUT  64
#define S_SZ   16
#define K_TOT  1024   // S_SZ * F_IN

#define M_TILE 128
#define BK     64
#define NHALF  8      // K-steps per block (K split in 2)
#define THREADS 512   // 8 waves: wave grid 4 (M) x 2 (N)

// LDS row stride in bf16 elements: 64 + 8 pad = 72 (144 B rows): <=2-way
// bank aliasing on ds_read_b128 (free per m136)
#define LDSTRIDE 72

typedef __attribute__((ext_vector_type(8))) short short8;  // 8 bf16
typedef __attribute__((ext_vector_type(4))) float f32x4;
typedef unsigned short u16;
typedef unsigned int   u32;

static __device__ __forceinline__ u32 packbf2(float a, float b) {
    // low 16 = a, high 16 = b (RNE); compiler emits v_cvt_pk_bf16_f32
    __hip_bfloat162 h = __float22bfloat162_rn(make_float2(a, b));
    union { __hip_bfloat162 h; u32 u; } c; c.h = h;
    return c.u;
}

// K-split grouped GEMM: block (g, mt, kh) computes the kh-th K-half of the
// (g, mt) output tile and atomicAdd's its partial into out (zeroed by the
// launcher's memset). Traffic identical to the R6 kernel; 2 independent
// blocks/CU so their barrier groups cover each other's stalls.
__global__ __launch_bounds__(THREADS, 4)   // 4 waves/EU = 2 blocks/CU
void sparse_linear_kernel(const float* __restrict__ x,
                          const int*   __restrict__ idx,
                          const float* __restrict__ W,
                          const float* __restrict__ bias,
                          float*       __restrict__ out)
{
    __shared__ u16 Alds[2][M_TILE * LDSTRIDE];
    __shared__ u16 Wlds[2][F_OUT * LDSTRIDE];

    const int blk   = blockIdx.x;            // 0..511
    const int g     = blk & 127;             // co-resident blk, blk+256: same g
    const int rest  = blk >> 7;              // 0..3
    const int mt    = rest & 1;
    const int kh    = rest >> 1;              // K half
    const int bbase = mt * M_TILE;

    const int tid  = threadIdx.x;
    const int wave = tid >> 6;
    const int lane = tid & 63;
    const int wr   = wave >> 1;    // 0..3 (M, 32 rows)
    const int wc   = wave & 1;     // 0..1 (N, 32 cols)
    const int lmod = lane & 15;
    const int ldiv = lane >> 4;

    // ---- A staging: 4 chunks, id = tid + i*512 in 0..2047 ----
    const float* aptr[4]; int lofsA[4];
    #pragma unroll
    for (int i = 0; i < 4; ++i) {
        int id = tid + i * THREADS;
        int m  = id >> 4;                  // 0..127
        int f  = (id & 15) << 2;           // float col
        aptr[i]  = x + (size_t)(bbase + m) * (N_IN * F_IN) + f;
        lofsA[i] = m * (LDSTRIDE * 2) + f * 2;
    }
    // ---- W staging: 2 chunks (kh base folded in) ----
    const float* wptr[2]; int lofsW[2];
    #pragma unroll
    for (int i = 0; i < 2; ++i) {
        int id = tid + i * THREADS;
        int o  = id >> 4;                  // 0..63
        int f  = (id & 15) << 2;
        wptr[i]  = W + (size_t)g * (F_OUT * K_TOT) + (size_t)o * K_TOT
                     + kh * (NHALF * BK) + f;
        lofsW[i] = o * (LDSTRIDE * 2) + f * 2;
    }

    int rows[NHALF];
    #pragma unroll
    for (int s = 0; s < NHALF; ++s)
        rows[s] = idx[g * S_SZ + kh * NHALF + s];   // uniform -> SGPR

    f32x4  acc[2][2] = {};
    float4 ra[2][4], rw[2][2];             // depth-2 register sets

    #define LOADT(t, s)                                                        \
        {                                                                      \
            const int row = rows[t];                                           \
            _Pragma("unroll")                                                  \
            for (int i = 0; i < 4; ++i)                                        \
                ra[s][i] = *reinterpret_cast<const float4*>(aptr[i] + row * F_IN); \
            _Pragma("unroll")                                                  \
            for (int i = 0; i < 2; ++i)                                        \
                rw[s][i] = *reinterpret_cast<const float4*>(wptr[i] + (t) * BK);   \
        }

    #define STORET(s, buf)                                                     \
        {                                                                      \
            _Pragma("unroll")                                                  \
            for (int i = 0; i < 4; ++i) {                                      \
                uint2 p;                                                       \
                p.x = packbf2(ra[s][i].x, ra[s][i].y);                         \
                p.y = packbf2(ra[s][i].z, ra[s][i].w);                         \
                *reinterpret_cast<uint2*>(                                     \
                    reinterpret_cast<char*>(Alds[buf]) + lofsA[i]) = p;        \
            }                                                                  \
            _Pragma("unroll")                                                  \
            for (int i = 0; i < 2; ++i) {                                      \
                uint2 p;                                                       \
                p.x = packbf2(rw[s][i].x, rw[s][i].y);                         \
                p.y = packbf2(rw[s][i].z, rw[s][i].w);                         \
                *reinterpret_cast<uint2*>(                                     \
                    reinterpret_cast<char*>(Wlds[buf]) + lofsW[i]) = p;        \
            }                                                                  \
        }

    #define COMPUTE(buf)                                                       \
        {                                                                      \
            _Pragma("unroll")                                                  \
            for (int ks = 0; ks < 2; ++ks) {                                   \
                const int kb = ks * 32 + (ldiv << 3);                          \
                short8 a[2], bfr[2];                                           \
                _Pragma("unroll")                                              \
                for (int mi = 0; mi < 2; ++mi)                                 \
                    a[mi] = *reinterpret_cast<const short8*>(                  \
                        reinterpret_cast<const char*>(Alds[buf]) +             \
                        (wr * 32 + mi * 16 + lmod) * (LDSTRIDE * 2) + kb * 2); \
                _Pragma("unroll")                                              \
                for (int ni = 0; ni < 2; ++ni)                                 \
                    bfr[ni] = *reinterpret_cast<const short8*>(                \
                        reinterpret_cast<const char*>(Wlds[buf]) +             \
                        (wc * 32 + ni * 16 + lmod) * (LDSTRIDE * 2) + kb * 2); \
                _Pragma("unroll")                                              \
                for (int mi = 0; mi < 2; ++mi)                                 \
                    _Pragma("unroll")                                          \
                    for (int ni = 0; ni < 2; ++ni)                             \
                        acc[mi][ni] = __builtin_amdgcn_mfma_f32_16x16x32_bf16( \
                            a[mi], bfr[ni], acc[mi][ni], 0, 0, 0);             \
            }                                                                  \
        }

    // lgkmcnt-only barrier (R6-proven with reg staging): ds ops drained,
    // global loads roll across; reg deps force compiler-counted vmcnt waits.
    #define ROLL_BARRIER()                                                     \
        {                                                                      \
            asm volatile("s_waitcnt lgkmcnt(0)" ::: "memory");                 \
            __builtin_amdgcn_s_barrier();                                      \
            asm volatile("" ::: "memory");                                     \
        }

    // ---- prologue: 2 load sets in flight, buffer 0 staged ----
    LOADT(0, 0);
    LOADT(1, 1);
    STORET(0, 0);          // counted wait on set 0 only (set 1 in flight)
    ROLL_BARRIER();

    // ---- main loop: rolling depth-2 pipeline over 8 K-steps ----
    #pragma unroll
    for (int t = 0; t < NHALF; ++t) {
        if (t + 2 < NHALF) LOADT(t + 2, t & 1);          // issue early
        COMPUTE(t & 1);
        if (t + 1 < NHALF) {
            STORET((t + 1) & 1, (t + 1) & 1);            // waits set t+1 only
            ROLL_BARRIER();
        }
    }

    // ---- epilogue: atomic partial accumulate (out zeroed by launcher) ----
    const int rowbase = bbase + wr * 32 + (ldiv << 2);
    #pragma unroll
    for (int ni = 0; ni < 2; ++ni) {
        const int o  = wc * 32 + ni * 16 + lmod;
        const float bv = (kh == 0) ? bias[g * F_OUT + o] : 0.0f;
        #pragma unroll
        for (int mi = 0; mi < 2; ++mi) {
            #pragma unroll
            for (int r = 0; r < 4; ++r) {
                const int brow = rowbase + mi * 16 + r;
                atomicAdd(&out[(size_t)brow * (G_SZ * F_OUT) + g * F_OUT + o],
                          acc[mi][ni][r] + bv);
            }
        }
    }
}

extern "C" void kernel_launch(void* const* d_in, const int* in_sizes, int n_in,
                              void* d_out, int out_size, void* d_ws, size_t ws_size,
                              hipStream_t stream) {
    const float* x    = (const float*)d_in[0];
    const int*   idx  = (const int*)d_in[1];
    const float* W    = (const float*)d_in[2];
    const float* bias = (const float*)d_in[3];
    float*       out  = (float*)d_out;

    // zero-init the accumulation target (re-runs on every graph replay)
    hipMemsetAsync(out, 0, (size_t)out_size * sizeof(float), stream);

    sparse_linear_kernel<<<dim3(512), dim3(THREADS), 0, stream>>>(
        x, idx, W, bias, out);
}

// Round 14
// 23.916 us; speedup vs baseline: 1.5587x; 1.5587x over previous
//
#include <hip/hip_runtime.h>
#include <hip/hip_bf16.h>

#define B_SZ   256
#define N_IN   128
#define F_IN   64
#define G_SZ   128
#define F_OUT  64
#define S_SZ   16
#define K_TOT  1024   // S_SZ * F_IN

#define M_TILE 128
#define BK     64
#define NSTEP  16     // K_TOT / BK
#define THREADS 512   // 8 waves: wave grid 4 (M) x 2 (N)

// LDS row stride in bf16 elements: 64 + 8 pad = 72 (144 B rows): <=2-way
// bank aliasing on ds_read_b128 (free per m136); rows stay 16B-aligned.
#define LDSTRIDE 72

typedef __attribute__((ext_vector_type(8))) short short8;  // 8 bf16
typedef __attribute__((ext_vector_type(4))) float f32x4;
typedef unsigned short u16;
typedef unsigned int   u32;

static __device__ __forceinline__ u32 packbf2(float a, float b) {
    // low 16 = a, high 16 = b (RNE); compiler emits v_cvt_pk_bf16_f32
    __hip_bfloat162 h = __float22bfloat162_rn(make_float2(a, b));
    union { __hip_bfloat162 h; u32 u; } c; c.h = h;
    return c.u;
}

// R6 structure (best: 23.7 us) with wide-write staging: each thread stages
// 8 consecutive floats of one row (2x float4 load -> 1x ds_write_b128),
// halving LDS-write instruction count (6x b64 -> 3x b128) at identical bytes.
__global__ __launch_bounds__(THREADS)
void sparse_linear_kernel(const float* __restrict__ x,
                          const int*   __restrict__ idx,
                          const float* __restrict__ W,
                          const float* __restrict__ bias,
                          float*       __restrict__ out)
{
    __shared__ u16 Alds[2][M_TILE * LDSTRIDE];
    __shared__ u16 Wlds[2][F_OUT * LDSTRIDE];

    const int blk   = blockIdx.x;
    const int g     = blk & 127;   // blk, blk+128 share W[g]; 128%8==0 -> same XCD
    const int mt    = blk >> 7;
    const int bbase = mt * M_TILE;

    const int tid  = threadIdx.x;
    const int wave = tid >> 6;
    const int lane = tid & 63;
    const int wr   = wave >> 1;    // 0..3 (M, 32 rows)
    const int wc   = wave & 1;     // 0..1 (N, 32 cols)
    const int lmod = lane & 15;
    const int ldiv = lane >> 4;

    // ---- A staging: 2 chunks, id = tid + i*512 in 0..1023 ----
    // m = id>>3 (0..127), f = (id&7)*8 (8 consecutive floats of row m)
    const float* aptr[2]; int lofsA[2];
    #pragma unroll
    for (int i = 0; i < 2; ++i) {
        int id = tid + i * THREADS;
        int m  = id >> 3;
        int f  = (id & 7) << 3;
        aptr[i]  = x + (size_t)(bbase + m) * (N_IN * F_IN) + f;
        lofsA[i] = m * (LDSTRIDE * 2) + f * 2;      // byte offset, 16B aligned
    }
    // ---- W staging: 1 chunk, tid in 0..511 -> o = tid>>3, f = (tid&7)*8 ----
    const float* wptr; int lofsW;
    {
        int o  = tid >> 3;
        int f  = (tid & 7) << 3;
        wptr  = W + (size_t)g * (F_OUT * K_TOT) + (size_t)o * K_TOT + f;
        lofsW = o * (LDSTRIDE * 2) + f * 2;
    }

    int rows[NSTEP];
    #pragma unroll
    for (int s = 0; s < NSTEP; ++s) rows[s] = idx[g * S_SZ + s];  // uniform -> SGPR

    f32x4  acc[2][2] = {};
    float4 ra[3][4], rw[3][2];     // depth-3 sets: A 2 chunks x 2 halves, W 2 halves

    #define LOADT(t, s)                                                        \
        {                                                                      \
            const int row = rows[t];                                           \
            _Pragma("unroll")                                                  \
            for (int i = 0; i < 2; ++i) {                                      \
                ra[s][2 * i]     = *reinterpret_cast<const float4*>(aptr[i] + row * F_IN);     \
                ra[s][2 * i + 1] = *reinterpret_cast<const float4*>(aptr[i] + row * F_IN + 4); \
            }                                                                  \
            rw[s][0] = *reinterpret_cast<const float4*>(wptr + (t) * BK);      \
            rw[s][1] = *reinterpret_cast<const float4*>(wptr + (t) * BK + 4);  \
        }

    #define STORET(s, buf)                                                     \
        {                                                                      \
            _Pragma("unroll")                                                  \
            for (int i = 0; i < 2; ++i) {                                      \
                uint4 q;                                                       \
                q.x = packbf2(ra[s][2 * i].x,     ra[s][2 * i].y);             \
                q.y = packbf2(ra[s][2 * i].z,     ra[s][2 * i].w);             \
                q.z = packbf2(ra[s][2 * i + 1].x, ra[s][2 * i + 1].y);         \
                q.w = packbf2(ra[s][2 * i + 1].z, ra[s][2 * i + 1].w);         \
                *reinterpret_cast<uint4*>(                                     \
                    reinterpret_cast<char*>(Alds[buf]) + lofsA[i]) = q;        \
            }                                                                  \
            {                                                                  \
                uint4 q;                                                       \
                q.x = packbf2(rw[s][0].x, rw[s][0].y);                         \
                q.y = packbf2(rw[s][0].z, rw[s][0].w);                         \
                q.z = packbf2(rw[s][1].x, rw[s][1].y);                         \
                q.w = packbf2(rw[s][1].z, rw[s][1].w);                         \
                *reinterpret_cast<uint4*>(                                     \
                    reinterpret_cast<char*>(Wlds[buf]) + lofsW) = q;           \
            }                                                                  \
        }

    #define COMPUTE(buf)                                                       \
        {                                                                      \
            _Pragma("unroll")                                                  \
            for (int ks = 0; ks < 2; ++ks) {                                   \
                const int kb = ks * 32 + (ldiv << 3);                          \
                short8 a[2], bfr[2];                                           \
                _Pragma("unroll")                                              \
                for (int mi = 0; mi < 2; ++mi)                                 \
                    a[mi] = *reinterpret_cast<const short8*>(                  \
                        reinterpret_cast<const char*>(Alds[buf]) +             \
                        (wr * 32 + mi * 16 + lmod) * (LDSTRIDE * 2) + kb * 2); \
                _Pragma("unroll")                                              \
                for (int ni = 0; ni < 2; ++ni)                                 \
                    bfr[ni] = *reinterpret_cast<const short8*>(                \
                        reinterpret_cast<const char*>(Wlds[buf]) +             \
                        (wc * 32 + ni * 16 + lmod) * (LDSTRIDE * 2) + kb * 2); \
                _Pragma("unroll")                                              \
                for (int mi = 0; mi < 2; ++mi)                                 \
                    _Pragma("unroll")                                          \
                    for (int ni = 0; ni < 2; ++ni)                             \
                        acc[mi][ni] = __builtin_amdgcn_mfma_f32_16x16x32_bf16( \
                            a[mi], bfr[ni], acc[mi][ni], 0, 0, 0);             \
            }                                                                  \
        }

    // lgkmcnt-only barrier: ds ops drained (own writes visible, own reads of
    // the buffer about to be overwritten done); global loads stay in flight.
    // Reg deps give compiler-counted vmcnt waits at STORET (R6-proven).
    #define ROLL_BARRIER()                                                     \
        {                                                                      \
            asm volatile("s_waitcnt lgkmcnt(0)" ::: "memory");                 \
            __builtin_amdgcn_s_barrier();                                      \
            asm volatile("" ::: "memory");                                     \
        }

    // ---- prologue: 3 load sets in flight, buffer 0 staged ----
    LOADT(0, 0);
    LOADT(1, 1);
    LOADT(2, 2);
    STORET(0, 0);          // counted wait: set 0 only (sets 1,2 stay in flight)
    ROLL_BARRIER();

    // ---- main loop: rolling depth-3 pipeline; vmcnt never drained to 0 ----
    #pragma unroll
    for (int t = 0; t < NSTEP; ++t) {
        if (t + 3 < NSTEP) LOADT(t + 3, t % 3);          // issue early
        COMPUTE(t & 1);
        if (t + 1 < NSTEP) {
            STORET((t + 1) % 3, (t + 1) & 1);            // waits set t+1 only
            ROLL_BARRIER();
        }
    }

    // ---- epilogue: C frag col = lane&15, row = (lane>>4)*4 + r ----
    const int rowbase = bbase + wr * 32 + (ldiv << 2);
    #pragma unroll
    for (int ni = 0; ni < 2; ++ni) {
        const int o  = wc * 32 + ni * 16 + lmod;
        const float bv = bias[g * F_OUT + o];
        #pragma unroll
        for (int mi = 0; mi < 2; ++mi) {
            #pragma unroll
            for (int r = 0; r < 4; ++r) {
                const int brow = rowbase + mi * 16 + r;
                out[(size_t)brow * (G_SZ * F_OUT) + g * F_OUT + o] = acc[mi][ni][r] + bv;
            }
        }
    }
}

extern "C" void kernel_launch(void* const* d_in, const int* in_sizes, int n_in,
                              void* d_out, int out_size, void* d_ws, size_t ws_size,
                              hipStream_t stream) {
    const float* x    = (const float*)d_in[0];
    const int*   idx  = (const int*)d_in[1];
    const float* W    = (const float*)d_in[2];
    const float* bias = (const float*)d_in[3];
    float*       out  = (float*)d_out;

    sparse_linear_kernel<<<dim3(G_SZ * (B_SZ / M_TILE)), dim3(THREADS), 0, stream>>>(
        x, idx, W, bias, out);
}